// Round 1
// 739.796 us; speedup vs baseline: 1.3388x; 1.3388x over previous
//
#include <hip/hip_runtime.h>

#define SEQ   4096
#define NB    2
#define NH    16
#define HD    128
#define TOPK  128
#define MDIM  (NB*SEQ)     // 8192
#define NDIM  2048
#define KDIM  2048

typedef unsigned short u16;
typedef __bf16  v8bf __attribute__((ext_vector_type(8)));
typedef float   v4f  __attribute__((ext_vector_type(4)));

__device__ __forceinline__ u16 f2b(float f) {               // fp32 -> bf16 RNE
    unsigned u = __float_as_uint(f);
    return (u16)((u + 0x7fffu + ((u >> 16) & 1u)) >> 16);
}
__device__ __forceinline__ float b2f(u16 h) {
    return __uint_as_float(((unsigned)h) << 16);
}

#define ASYNC16(gsrc, ldst) \
    __builtin_amdgcn_global_load_lds( \
        (const __attribute__((address_space(1))) unsigned int*)(gsrc), \
        (__attribute__((address_space(3))) unsigned int*)(ldst), 16, 0, 0)

// ---------------------------------------------------------------------------
// fp32 -> (bf16 hi, bf16 lo residual), 4 elems/thread
// ---------------------------------------------------------------------------
__global__ __launch_bounds__(256) void split_f32(const float* __restrict__ in,
                                                 u16* __restrict__ hi,
                                                 u16* __restrict__ lo, long n)
{
    long i = ((long)blockIdx.x * 256 + threadIdx.x) * 4;
    if (i >= n) return;
    float4 v = *(const float4*)(in + i);
    float vv[4] = {v.x, v.y, v.z, v.w};
    u16 h[4], l[4];
#pragma unroll
    for (int j = 0; j < 4; ++j) {
        h[j] = f2b(vv[j]);
        l[j] = f2b(vv[j] - b2f(h[j]));
    }
    uint2 ph, pl;
    ph.x = (unsigned)h[0] | ((unsigned)h[1] << 16);
    ph.y = (unsigned)h[2] | ((unsigned)h[3] << 16);
    pl.x = (unsigned)l[0] | ((unsigned)l[1] << 16);
    pl.y = (unsigned)l[2] | ((unsigned)l[3] << 16);
    *(uint2*)(hi + i) = ph;
    *(uint2*)(lo + i) = pl;
}

// fp32 -> bf16, 4 elems/thread
__global__ __launch_bounds__(256) void cvt_bf16(const float* __restrict__ in,
                                                u16* __restrict__ outb, long n)
{
    long i = ((long)blockIdx.x * 256 + threadIdx.x) * 4;
    if (i >= n) return;
    float4 v = *(const float4*)(in + i);
    uint2 p;
    p.x = (unsigned)f2b(v.x) | ((unsigned)f2b(v.y) << 16);
    p.y = (unsigned)f2b(v.z) | ((unsigned)f2b(v.w) << 16);
    *(uint2*)(outb + i) = p;
}

// ---------------------------------------------------------------------------
// MFMA bf16 GEMM (NT): C[M,2048] = A[M,2048](bf16) @ W[2048,2048](bf16)^T
// 256x256 tile, BK=64, 512 thr = 8 waves (2M x 4N), 8-phase schedule:
//   T2 swizzled LDS (inverse-swizzled global src -> linear global_load_lds,
//   swizzled ds_read), T3 8-phase interleave, T4 counted vmcnt (never 0 in
//   the main loop), T5 setprio around each 16-MFMA cluster, XCD block swizzle.
// Stage unit = 16KB strip-pair; liveness calendar (iter i, tile T=2i):
//   p0:SA(T+1,1) p1:SB(T+1,1) p2:SA(T+2,0) p3:SB(T+2,0)+vmcnt(4)
//   p4:SA(T+2,1) p5:SB(T+2,1) p6:SA(T+3,0) p7:SB(T+3,0)+vmcnt(4)
// Each staged region was last ds_read >=1 barrier before its stage issue;
// vmcnt(4) guarantees the tile read in the following 4 phases has landed.
// ---------------------------------------------------------------------------
#define GM_STORE_F32 0
#define GM_ACC_F32   1
#define GM_STORE_B16 2

#define BAR    __builtin_amdgcn_s_barrier()
#define LGK0   do { asm volatile("s_waitcnt lgkmcnt(0)" ::: "memory"); \
                    __builtin_amdgcn_sched_barrier(0); } while (0)
#define VMW(n) asm volatile("s_waitcnt vmcnt(" #n ")" ::: "memory")

__global__ __launch_bounds__(512, 2) void gemm256(const u16* __restrict__ A,
                                                  const u16* __restrict__ W,
                                                  float* __restrict__ Cf,
                                                  u16* __restrict__ Cb,
                                                  int mode)
{
    __shared__ __attribute__((aligned(16))) u16 S[65536];   // 128 KiB: A dbuf | B dbuf

    const int t    = threadIdx.x;
    const int swz  = (blockIdx.x & 7) * 32 + (blockIdx.x >> 3);  // XCD-chunked
    const int bm   = swz >> 3, bn = swz & 7;
    const int lane = t & 63;
    const int wm   = (t >> 6) >> 2, wn = (t >> 6) & 3;
    const int mr   = lane & 15, q4 = lane >> 4;

    // staging geometry: linear LDS fill; source chunk pre-swizzled (rule 21)
    const int rA  = t >> 3;                              // 0..63, row in strip
    const int cc8 = ((t & 7) ^ (rA & 7)) * 8;            // swizzled src chunk
    const int rB  = (t >> 8) * 64 + (rA & 31);
    const u16* Agp = A + (long)(bm * 256 + rA) * KDIM + cc8;
    const u16* Wgp = W + (long)(bn * 256 + rB) * KDIM + cc8;
    u16* ldA = S +         rA * 64 + (t & 7) * 8;
    u16* ldB = S + 32768 + rB * 64 + (t & 7) * 8;

    // A strip i of tile kt: rows {i*64..i*64+63} u {128+i*64..}, 2x16B/thread
#define STAGE_A(kt, i) do { \
        const u16* g_ = Agp + (long)(i) * 64 * KDIM + (kt) * 64; \
        u16* d_ = ldA + ((kt) & 1) * 16384 + (i) * 4096; \
        ASYNC16(g_, d_); ASYNC16(g_ + 128 * KDIM, d_ + 8192); \
    } while (0)
    // B strip-quad j of tile kt: rows {j*32+64k+(0..31), k=0..3}
#define STAGE_B(kt, j) do { \
        const u16* g_ = Wgp + (long)(j) * 32 * KDIM + (kt) * 64; \
        u16* d_ = ldB + ((kt) & 1) * 16384 + (j) * 2048; \
        ASYNC16(g_, d_); ASYNC16(g_ + 128 * KDIM, d_ + 8192); \
    } while (0)

    v4f acc[8][4];
#pragma unroll
    for (int a = 0; a < 8; ++a)
#pragma unroll
        for (int c = 0; c < 4; ++c)
            acc[a][c] = (v4f){0.f, 0.f, 0.f, 0.f};

    v8bf aF[4][2], bF[2][2][2];
#define LDA(b, i) do { \
        _Pragma("unroll") for (int mt = 0; mt < 4; ++mt) { \
            const int r_ = wm * 128 + (i) * 64 + mt * 16 + mr; \
            _Pragma("unroll") for (int ks = 0; ks < 2; ++ks) \
                aF[mt][ks] = *(const v8bf*)&S[(b) * 16384 + r_ * 64 + \
                                    (((ks * 4 + q4) ^ (r_ & 7)) * 8)]; \
        } } while (0)
#define LDB(b, j) do { \
        _Pragma("unroll") for (int nt = 0; nt < 2; ++nt) { \
            const int r_ = wn * 64 + (j) * 32 + nt * 16 + mr; \
            _Pragma("unroll") for (int ks = 0; ks < 2; ++ks) \
                bF[j][nt][ks] = *(const v8bf*)&S[32768 + (b) * 16384 + r_ * 64 + \
                                    (((ks * 4 + q4) ^ (r_ & 7)) * 8)]; \
        } } while (0)
#define MMA(i, j) do { \
        __builtin_amdgcn_s_setprio(1); \
        _Pragma("unroll") for (int mt = 0; mt < 4; ++mt) \
        _Pragma("unroll") for (int nt = 0; nt < 2; ++nt) \
        _Pragma("unroll") for (int ks = 0; ks < 2; ++ks) \
            acc[(i) * 4 + mt][(j) * 2 + nt] = \
                __builtin_amdgcn_mfma_f32_16x16x32_bf16(aF[mt][ks], bF[j][nt][ks], \
                    acc[(i) * 4 + mt][(j) * 2 + nt], 0, 0, 0); \
        __builtin_amdgcn_s_setprio(0); \
    } while (0)

    // prologue: tile0 complete + tile1 front strips; allow tile1 in flight
    STAGE_A(0, 0); STAGE_B(0, 0); STAGE_A(0, 1); STAGE_B(0, 1);
    STAGE_A(1, 0); STAGE_B(1, 0);
    VMW(4); BAR;

    for (int it = 0; it < KDIM / 128 - 1; ++it) {
        const int T = 2 * it;
        LDA(0, 0); LDB(0, 0); STAGE_A(T + 1, 1);          BAR; LGK0; MMA(0, 0); BAR;
        LDB(0, 1);            STAGE_B(T + 1, 1);          BAR; LGK0; MMA(0, 1); BAR;
        LDA(0, 1);            STAGE_A(T + 2, 0);          BAR; LGK0; MMA(1, 0); BAR;
                              STAGE_B(T + 2, 0); VMW(4);  BAR;       MMA(1, 1); BAR;
        LDA(1, 0); LDB(1, 0); STAGE_A(T + 2, 1);          BAR; LGK0; MMA(0, 0); BAR;
        LDB(1, 1);            STAGE_B(T + 2, 1);          BAR; LGK0; MMA(0, 1); BAR;
        LDA(1, 1);            STAGE_A(T + 3, 0);          BAR; LGK0; MMA(1, 0); BAR;
                              STAGE_B(T + 3, 0); VMW(4);  BAR;       MMA(1, 1); BAR;
    }
    // final iteration (tiles 30,31): no forward staging past tile 31
    LDA(0, 0); LDB(0, 0); STAGE_A(31, 1);                 BAR; LGK0; MMA(0, 0); BAR;
    LDB(0, 1);            STAGE_B(31, 1);                 BAR; LGK0; MMA(0, 1); BAR;
    LDA(0, 1);                                            BAR; LGK0; MMA(1, 0); BAR;
                                             VMW(0);      BAR;       MMA(1, 1); BAR;
    LDA(1, 0); LDB(1, 0);                                 BAR; LGK0; MMA(0, 0); BAR;
    LDB(1, 1);                                            BAR; LGK0; MMA(0, 1); BAR;
    LDA(1, 1);                                            BAR; LGK0; MMA(1, 0); BAR;
                                                                     MMA(1, 1);

    // epilogue: C[row=.. (lane>>4)*4+r][col=.. lane&15]
    const int colb = bn * 256 + wn * 64 + mr;
    const int rowb = bm * 256 + wm * 128 + q4 * 4;
#pragma unroll
    for (int a = 0; a < 8; ++a) {
        const int ro = (a >> 2) * 64 + (a & 3) * 16;
#pragma unroll
        for (int r = 0; r < 4; ++r) {
            const long base = (long)(rowb + ro + r) * NDIM + colb;
#pragma unroll
            for (int c = 0; c < 4; ++c) {
                const float v = acc[a][c][r];
                const long off = base + (c >> 1) * 32 + (c & 1) * 16;
                if (mode == GM_STORE_F32)      Cf[off] = v;
                else if (mode == GM_ACC_F32)   Cf[off] += v;
                else                           Cb[off] = f2b(v);
            }
        }
    }
#undef STAGE_A
#undef STAGE_B
#undef LDA
#undef LDB
#undef MMA
}

// ---------------------------------------------------------------------------
// Fused score net on fp32 K (selection-critical, stays fp32 VALU)
// ---------------------------------------------------------------------------
__global__ __launch_bounds__(256) void scorenet(const float* __restrict__ Kb,
                                                const float* __restrict__ sw1,
                                                const float* __restrict__ sb1,
                                                const float* __restrict__ sw2,
                                                const float* __restrict__ sb2,
                                                float* __restrict__ scores)
{
    __shared__ float As[16][128];
    __shared__ float Bs[16][128];
    __shared__ float red[128][17];
    const int t  = threadIdx.x;
    const int tx = t & 15, ty = t >> 4;
    const int bm = blockIdx.x;
    const int lr = t >> 1;
    const int lc = (t & 1) * 8;
    const float* Ap = Kb + (long)(bm * 128 + lr) * HD + lc;
    const float* Wp = sw1 + lr * HD + lc;

    float acc[8][8];
#pragma unroll
    for (int i = 0; i < 8; ++i)
#pragma unroll
        for (int j = 0; j < 8; ++j) acc[i][j] = 0.f;

    for (int k0 = 0; k0 < HD; k0 += 16) {
        float4 a0 = *(const float4*)(Ap + k0);
        float4 a1 = *(const float4*)(Ap + k0 + 4);
        float4 b0 = *(const float4*)(Wp + k0);
        float4 b1 = *(const float4*)(Wp + k0 + 4);
        __syncthreads();
        As[lc+0][lr] = a0.x; As[lc+1][lr] = a0.y; As[lc+2][lr] = a0.z; As[lc+3][lr] = a0.w;
        As[lc+4][lr] = a1.x; As[lc+5][lr] = a1.y; As[lc+6][lr] = a1.z; As[lc+7][lr] = a1.w;
        Bs[lc+0][lr] = b0.x; Bs[lc+1][lr] = b0.y; Bs[lc+2][lr] = b0.z; Bs[lc+3][lr] = b0.w;
        Bs[lc+4][lr] = b1.x; Bs[lc+5][lr] = b1.y; Bs[lc+6][lr] = b1.z; Bs[lc+7][lr] = b1.w;
        __syncthreads();
#pragma unroll
        for (int kk = 0; kk < 16; ++kk) {
            float a[8], b[8];
            *(float4*)&a[0] = *(const float4*)&As[kk][ty * 8];
            *(float4*)&a[4] = *(const float4*)&As[kk][ty * 8 + 4];
            *(float4*)&b[0] = *(const float4*)&Bs[kk][tx * 8];
            *(float4*)&b[4] = *(const float4*)&Bs[kk][tx * 8 + 4];
#pragma unroll
            for (int i = 0; i < 8; ++i)
#pragma unroll
                for (int j = 0; j < 8; ++j)
                    acc[i][j] = fmaf(a[i], b[j], acc[i][j]);
        }
    }

    float b1v[8], w2v[8];
#pragma unroll
    for (int j = 0; j < 8; ++j) {
        b1v[j] = sb1[tx * 8 + j];
        w2v[j] = sw2[tx * 8 + j];
    }
#pragma unroll
    for (int i = 0; i < 8; ++i) {
        float p = 0.f;
#pragma unroll
        for (int j = 0; j < 8; ++j)
            p += fmaxf(acc[i][j] + b1v[j], 0.f) * w2v[j];
        red[ty * 8 + i][tx] = p;
    }
    __syncthreads();
    if (t < 128) {
        float s = sb2[0];
#pragma unroll
        for (int c = 0; c < 16; ++c) s += red[t][c];
        long r = (long)bm * 128 + t;
        int b  = (int)(r >> 16);
        int si = (int)((r >> 4) & (SEQ - 1));
        int h  = (int)(r & (NH - 1));
        scores[((b * NH + h) << 12) + si] = s;
    }
}

// ---------------------------------------------------------------------------
// Exact top-128 per (b,h) via radix select; ties -> lowest indices.
// ---------------------------------------------------------------------------
__global__ __launch_bounds__(256) void topk_sel(const float* __restrict__ scores,
                                                int* __restrict__ sel)
{
    __shared__ unsigned keys[SEQ];
    __shared__ unsigned hist[256];
    __shared__ int scal2[2];
    __shared__ unsigned cntG;
    __shared__ unsigned short tpre[256];
    const int t  = threadIdx.x;
    const int bh = blockIdx.x;
    const float* sc = scores + (long)bh * SEQ;
    for (int i = t; i < SEQ; i += 256) {
        unsigned u = __float_as_uint(sc[i]);
        u = (u & 0x80000000u) ? ~u : (u | 0x80000000u);
        keys[i] = u;
    }
    unsigned prefix = 0;
    int rem = TOPK;
    const int i0 = t * 16;
    for (int shift = 24; shift >= 0; shift -= 8) {
        hist[t] = 0;
        __syncthreads();
        const unsigned pm = (shift == 24) ? 0u : (0xFFFFFFFFu << (shift + 8));
        for (int i = i0; i < i0 + 16; ++i) {
            unsigned k = keys[i];
            if (((k ^ prefix) & pm) == 0) atomicAdd(&hist[(k >> shift) & 255], 1u);
        }
        __syncthreads();
        if (t == 0) {
            int r = rem, chosen = 0;
            for (int b = 255; b >= 0; --b) {
                int c = (int)hist[b];
                if (c >= r) { chosen = b; break; }
                r -= c;
            }
            scal2[0] = chosen; scal2[1] = r;
        }
        __syncthreads();
        prefix |= ((unsigned)scal2[0]) << shift;
        rem = scal2[1];
        __syncthreads();
    }
    if (t == 0) cntG = 0;
    __syncthreads();
    const unsigned T = prefix;
    int myT = 0;
    for (int i = i0; i < i0 + 16; ++i) {
        unsigned k = keys[i];
        if (k > T) {
            unsigned p = atomicAdd(&cntG, 1u);
            sel[bh * TOPK + p] = i;
        } else if (k == T) myT++;
    }
    tpre[t] = (unsigned short)myT;
    __syncthreads();
    if (t == 0) {
        unsigned s = 0;
        for (int i = 0; i < 256; ++i) { unsigned c = tpre[i]; tpre[i] = (unsigned short)s; s += c; }
    }
    __syncthreads();
    const int base = TOPK - rem;
    int rank = tpre[t];
    for (int i = i0; i < i0 + 16; ++i) {
        if (keys[i] == T) {
            if (rank < rem) sel[bh * TOPK + base + rank] = i;
            rank++;
        }
    }
}

// ---------------------------------------------------------------------------
// Gather: K (fp32) -> ksb bf16 [bh][key][d] ; V (bf16) -> vsT bf16 [bh][d][key]
// ---------------------------------------------------------------------------
__global__ void gather_kv(const float* __restrict__ Kf, const u16* __restrict__ Vb,
                          const int* __restrict__ sel,
                          u16* __restrict__ ksb, u16* __restrict__ vsT)
{
    int bh = blockIdx.x >> 7;
    int j  = blockIdx.x & 127;
    int d  = threadIdx.x;
    int s  = sel[bh * TOPK + j];
    int b = bh >> 4, h = bh & (NH - 1);
    long src = ((long)(b * SEQ + s)) * NDIM + h * HD + d;
    ksb[((long)bh * TOPK + j) * HD + d] = f2b(Kf[src]);
    vsT[((long)bh * HD + d) * TOPK + j] = Vb[src];
}

// ---------------------------------------------------------------------------
// MFMA attention: block = 128 queries of one (b,h), 4 waves x 32 queries.
// ---------------------------------------------------------------------------
__device__ __forceinline__ int paddr(int row, int col) {   // u16 index into P
    int chunk = (col >> 3) ^ (row & 15);
    return row * 128 + chunk * 8 + (col & 7);
}

__global__ __launch_bounds__(256) void attn_mfma(const u16* __restrict__ Qb,
                                                 const u16* __restrict__ ksb,
                                                 const u16* __restrict__ vsT,
                                                 u16* __restrict__ outp)
{
    __shared__ __attribute__((aligned(16))) u16 P[128 * 128];  // 32 KB
    const int bh = blockIdx.x, qt = blockIdx.y;
    const int b = bh >> 4, h = bh & (NH - 1);
    const int t = threadIdx.x, lane = t & 63, w = t >> 6;
    const int mr = lane & 15, q4 = lane >> 4;
    const float scale = 0.08838834764831845f;   // 1/sqrt(128)

    const u16* q0p = Qb + ((long)(b * SEQ + qt * 128 + w * 32 + mr)) * NDIM
                        + h * HD + q4 * 8;
    v8bf aq[2][4];
#pragma unroll
    for (int ks = 0; ks < 4; ++ks) {
        aq[0][ks] = *(const v8bf*)(q0p + ks * 32);
        aq[1][ks] = *(const v8bf*)(q0p + 16 * NDIM + ks * 32);
    }

    const u16* kbase = ksb + (long)bh * TOPK * HD + mr * HD + q4 * 8;
    v4f acc[2][8];
#pragma unroll
    for (int i = 0; i < 2; ++i)
#pragma unroll
        for (int j = 0; j < 8; ++j) {
            acc[i][j][0] = 0.f; acc[i][j][1] = 0.f;
            acc[i][j][2] = 0.f; acc[i][j][3] = 0.f;
        }
#pragma unroll
    for (int ks = 0; ks < 4; ++ks) {
        v8bf bk[8];
#pragma unroll
        for (int nt = 0; nt < 8; ++nt)
            bk[nt] = *(const v8bf*)(kbase + (long)nt * 16 * HD + ks * 32);
#pragma unroll
        for (int mt = 0; mt < 2; ++mt)
#pragma unroll
            for (int nt = 0; nt < 8; ++nt)
                acc[mt][nt] = __builtin_amdgcn_mfma_f32_16x16x32_bf16(
                                  aq[mt][ks], bk[nt], acc[mt][nt], 0, 0, 0);
    }

#pragma unroll
    for (int mt = 0; mt < 2; ++mt)
#pragma unroll
        for (int r = 0; r < 4; ++r) {
            float mx = acc[mt][0][r];
#pragma unroll
            for (int nt = 1; nt < 8; ++nt) mx = fmaxf(mx, acc[mt][nt][r]);
#pragma unroll
            for (int m = 1; m < 16; m <<= 1) mx = fmaxf(mx, __shfl_xor(mx, m));
            float sum = 0.f;
#pragma unroll
            for (int nt = 0; nt < 8; ++nt) {
                float e = __expf((acc[mt][nt][r] - mx) * scale);
                acc[mt][nt][r] = e; sum += e;
            }
#pragma unroll
            for (int m = 1; m < 16; m <<= 1) sum += __shfl_xor(sum, m);
            float inv = 1.f / sum;
#pragma unroll
            for (int nt = 0; nt < 8; ++nt) acc[mt][nt][r] *= inv;
        }

#pragma unroll
    for (int mt = 0; mt < 2; ++mt)
#pragma unroll
        for (int nt = 0; nt < 8; ++nt)
#pragma unroll
            for (int r = 0; r < 4; ++r)
                P[paddr(w * 32 + mt * 16 + q4 * 4 + r, nt * 16 + mr)] =
                    f2b(acc[mt][nt][r]);
    __syncthreads();

    const u16* vbase = vsT + (long)bh * HD * TOPK + mr * TOPK + q4 * 8;
    v4f acc2[2][8];
#pragma unroll
    for (int i = 0; i < 2; ++i)
#pragma unroll
        for (int j = 0; j < 8; ++j) {
            acc2[i][j][0] = 0.f; acc2[i][j][1] = 0.f;
            acc2[i][j][2] = 0.f; acc2[i][j][3] = 0.f;
        }
#pragma unroll
    for (int ks = 0; ks < 4; ++ks) {
        v8bf ap[2];
        ap[0] = *(const v8bf*)&P[paddr(w * 32 + mr,      ks * 32 + q4 * 8)];
        ap[1] = *(const v8bf*)&P[paddr(w * 32 + 16 + mr, ks * 32 + q4 * 8)];
        v8bf bv[8];
#pragma unroll
        for (int nt = 0; nt < 8; ++nt)
            bv[nt] = *(const v8bf*)(vbase + (long)nt * 16 * TOPK + ks * 32);
#pragma unroll
        for (int mt = 0; mt < 2; ++mt)
#pragma unroll
            for (int nt = 0; nt < 8; ++nt)
                acc2[mt][nt] = __builtin_amdgcn_mfma_f32_16x16x32_bf16(
                                   ap[mt], bv[nt], acc2[mt][nt], 0, 0, 0);
    }
    __syncthreads();

#pragma unroll
    for (int mt = 0; mt < 2; ++mt)
#pragma unroll
        for (int nt = 0; nt < 8; ++nt)
#pragma unroll
            for (int r = 0; r < 4; ++r)
                P[paddr(w * 32 + mt * 16 + q4 * 4 + r, nt * 16 + mr)] =
                    f2b(acc2[mt][nt][r]);
    __syncthreads();

    u16* obase = outp + ((long)(b * SEQ + qt * 128)) * NDIM + h * HD;
    for (int f = t; f < 2048; f += 256) {
        int row = f >> 4, cc = f & 15;
        uint4 val = *(const uint4*)&P[row * 128 + (cc ^ (row & 15)) * 8];
        *(uint4*)(obase + (long)row * NDIM + cc * 8) = val;
    }
}

// ---------------------------------------------------------------------------
extern "C" void kernel_launch(void* const* d_in, const int* in_sizes, int n_in,
                              void* d_out, int out_size, void* d_ws, size_t ws_size,
                              hipStream_t stream)
{
    const float* x   = (const float*)d_in[0];
    const float* wq  = (const float*)d_in[1];
    const float* wk  = (const float*)d_in[2];
    const float* wv  = (const float*)d_in[3];
    const float* wo  = (const float*)d_in[4];
    const float* sw1 = (const float*)d_in[5];
    const float* sb1 = (const float*)d_in[6];
    const float* sw2 = (const float*)d_in[7];
    const float* sb2 = (const float*)d_in[8];
    float* out = (float*)d_out;

    // workspace layout (bytes), ~179.5 MiB total
    char* base = (char*)d_ws;
    u16*   xh      = (u16*)  base;                     // 33,554,432
    u16*   xl      = (u16*) (base + 33554432L);        // 33,554,432 (later: Qb)
    float* Kf      = (float*)(base + 67108864L);       // 67,108,864
    u16*   Vb      = (u16*) (base + 134217728L);       // 33,554,432 (later: AOb)
    u16*   W1      = (u16*) (base + 167772160L);       // 8,388,608
    u16*   W2      = (u16*) (base + 176160768L);       // 8,388,608
    float* scoresB = (float*)(base + 184549376L);      // 524,288
    int*   sel     = (int*) (base + 185073664L);       // 16,384
    u16*   ksb     = (u16*) (base + 185090048L);       // 1,048,576
    u16*   vsT     = (u16*) (base + 186138624L);       // 1,048,576
    u16*   Qb      = xl;                               // alias: xl dead after K passes
    u16*   AOb     = Vb;                               // alias: Vb dead after gather

    const long NX = (long)MDIM * NDIM;
    dim3 blk(256);
    const int g256 = (MDIM / 256) * (NDIM / 256);      // 256 blocks, 1/CU

    // precision splits / casts
    split_f32<<<16384, blk, 0, stream>>>(x,  xh, xl, NX);
    split_f32<<<4096,  blk, 0, stream>>>(wk, W1, W2, (long)NDIM * KDIM);
    // K = xh@wkh^T + xh@wkl^T + xl@wkh^T  (fp32-accurate K for selection)
    gemm256<<<g256, 512, 0, stream>>>(xh, W1, Kf, nullptr, GM_STORE_F32);
    gemm256<<<g256, 512, 0, stream>>>(xh, W2, Kf, nullptr, GM_ACC_F32);
    gemm256<<<g256, 512, 0, stream>>>(xl, W1, Kf, nullptr, GM_ACC_F32);
    // Q, V in plain bf16
    cvt_bf16<<<4096, blk, 0, stream>>>(wq, W1, (long)NDIM * KDIM);
    cvt_bf16<<<4096, blk, 0, stream>>>(wv, W2, (long)NDIM * KDIM);
    gemm256<<<g256, 512, 0, stream>>>(xh, W1, nullptr, Qb, GM_STORE_B16);
    gemm256<<<g256, 512, 0, stream>>>(xh, W2, nullptr, Vb, GM_STORE_B16);
    // selection path (fp32 K)
    scorenet<<<(MDIM * NH) / 128, blk, 0, stream>>>(Kf, sw1, sb1, sw2, sb2, scoresB);
    topk_sel<<<NB * NH, blk, 0, stream>>>(scoresB, sel);
    gather_kv<<<NB * NH * TOPK, 128, 0, stream>>>(Kf, Vb, sel, ksb, vsT);
    // MFMA attention -> AOb
    attn_mfma<<<dim3(NB * NH, SEQ / 128), blk, 0, stream>>>(Qb, ksb, vsT, AOb);
    // output projection
    cvt_bf16<<<4096, blk, 0, stream>>>(wo, W1, (long)NDIM * KDIM);
    gemm256<<<g256, 512, 0, stream>>>(AOb, W1, out, nullptr, GM_STORE_F32);
}

// Round 2
// 666.977 us; speedup vs baseline: 1.4849x; 1.1092x over previous
//
#include <hip/hip_runtime.h>

#define SEQ   4096
#define NB    2
#define NH    16
#define HD    128
#define TOPK  128
#define MDIM  (NB*SEQ)     // 8192
#define NDIM  2048
#define KDIM  2048

typedef unsigned short u16;
typedef __bf16  v8bf __attribute__((ext_vector_type(8)));
typedef float   v4f  __attribute__((ext_vector_type(4)));

__device__ __forceinline__ u16 f2b(float f) {               // fp32 -> bf16 RNE
    unsigned u = __float_as_uint(f);
    return (u16)((u + 0x7fffu + ((u >> 16) & 1u)) >> 16);
}
__device__ __forceinline__ float b2f(u16 h) {
    return __uint_as_float(((unsigned)h) << 16);
}

#define ASYNC16(gsrc, ldst) \
    __builtin_amdgcn_global_load_lds( \
        (const __attribute__((address_space(1))) unsigned int*)(gsrc), \
        (__attribute__((address_space(3))) unsigned int*)(ldst), 16, 0, 0)

#define BAR     __builtin_amdgcn_s_barrier()
#define SCB0    __builtin_amdgcn_sched_barrier(0)
#define SP1     __builtin_amdgcn_s_setprio(1)
#define SP0     __builtin_amdgcn_s_setprio(0)
#define LGKC(n) do { asm volatile("s_waitcnt lgkmcnt(" #n ")" ::: "memory"); \
                     __builtin_amdgcn_sched_barrier(0); } while (0)
#define VMW(n)  asm volatile("s_waitcnt vmcnt(" #n ")" ::: "memory")

// ---------------------------------------------------------------------------
// fp32 -> (bf16 hi, bf16 lo residual), 4 elems/thread
// ---------------------------------------------------------------------------
__global__ __launch_bounds__(256) void split_f32(const float* __restrict__ in,
                                                 u16* __restrict__ hi,
                                                 u16* __restrict__ lo, long n)
{
    long i = ((long)blockIdx.x * 256 + threadIdx.x) * 4;
    if (i >= n) return;
    float4 v = *(const float4*)(in + i);
    float vv[4] = {v.x, v.y, v.z, v.w};
    u16 h[4], l[4];
#pragma unroll
    for (int j = 0; j < 4; ++j) {
        h[j] = f2b(vv[j]);
        l[j] = f2b(vv[j] - b2f(h[j]));
    }
    uint2 ph, pl;
    ph.x = (unsigned)h[0] | ((unsigned)h[1] << 16);
    ph.y = (unsigned)h[2] | ((unsigned)h[3] << 16);
    pl.x = (unsigned)l[0] | ((unsigned)l[1] << 16);
    pl.y = (unsigned)l[2] | ((unsigned)l[3] << 16);
    *(uint2*)(hi + i) = ph;
    *(uint2*)(lo + i) = pl;
}

// fp32 -> bf16, 4 elems/thread
__global__ __launch_bounds__(256) void cvt_bf16(const float* __restrict__ in,
                                                u16* __restrict__ outb, long n)
{
    long i = ((long)blockIdx.x * 256 + threadIdx.x) * 4;
    if (i >= n) return;
    float4 v = *(const float4*)(in + i);
    uint2 p;
    p.x = (unsigned)f2b(v.x) | ((unsigned)f2b(v.y) << 16);
    p.y = (unsigned)f2b(v.z) | ((unsigned)f2b(v.w) << 16);
    *(uint2*)(outb + i) = p;
}

// ---------------------------------------------------------------------------
// MFMA bf16 GEMM (NT): C[M,2048] = A[M,2048](bf16) @ W[2048,2048](bf16)^T
// 256x256 tile, BK=64, 512 thr = 8 waves (2M x 4N), 8-phase schedule with
// counted vmcnt AND counted lgkmcnt (reads ordered [B][A-half0][A-half1],
// MFMA split in halves so the tail reads hide under the first 16 MFMA).
// ---------------------------------------------------------------------------
#define GM_STORE_F32 0
#define GM_ACC_F32   1
#define GM_STORE_B16 2

__global__ __launch_bounds__(512, 2) void gemm256(const u16* __restrict__ A,
                                                  const u16* __restrict__ W,
                                                  float* __restrict__ Cf,
                                                  u16* __restrict__ Cb,
                                                  int mode)
{
    __shared__ __attribute__((aligned(16))) u16 S[65536];   // 128 KiB

    const int t    = threadIdx.x;
    const int swz  = (blockIdx.x & 7) * 32 + (blockIdx.x >> 3);  // XCD-chunked
    const int bm   = swz >> 3, bn = swz & 7;
    const int lane = t & 63;
    const int wm   = (t >> 6) >> 2, wn = (t >> 6) & 3;
    const int mr   = lane & 15, q4 = lane >> 4;

    const int rA  = t >> 3;
    const int cc8 = ((t & 7) ^ (rA & 7)) * 8;
    const int rB  = (t >> 8) * 64 + (rA & 31);
    const u16* Agp = A + (long)(bm * 256 + rA) * KDIM + cc8;
    const u16* Wgp = W + (long)(bn * 256 + rB) * KDIM + cc8;
    u16* ldA = S +         rA * 64 + (t & 7) * 8;
    u16* ldB = S + 32768 + rB * 64 + (t & 7) * 8;

#define STAGE_A(kt, i) do { \
        const u16* g_ = Agp + (long)(i) * 64 * KDIM + (kt) * 64; \
        u16* d_ = ldA + ((kt) & 1) * 16384 + (i) * 4096; \
        ASYNC16(g_, d_); ASYNC16(g_ + 128 * KDIM, d_ + 8192); \
    } while (0)
#define STAGE_B(kt, j) do { \
        const u16* g_ = Wgp + (long)(j) * 32 * KDIM + (kt) * 64; \
        u16* d_ = ldB + ((kt) & 1) * 16384 + (j) * 2048; \
        ASYNC16(g_, d_); ASYNC16(g_ + 128 * KDIM, d_ + 8192); \
    } while (0)

    v4f acc[8][4];
#pragma unroll
    for (int a = 0; a < 8; ++a)
#pragma unroll
        for (int c = 0; c < 4; ++c)
            acc[a][c] = (v4f){0.f, 0.f, 0.f, 0.f};

    v8bf aF[4][2], bF[2][2][2];
#define LDB(b, j) do { \
        _Pragma("unroll") for (int nt = 0; nt < 2; ++nt) { \
            const int r_ = wn * 64 + (j) * 32 + nt * 16 + mr; \
            _Pragma("unroll") for (int ks = 0; ks < 2; ++ks) \
                bF[j][nt][ks] = *(const v8bf*)&S[32768 + (b) * 16384 + r_ * 64 + \
                                    (((ks * 4 + q4) ^ (r_ & 7)) * 8)]; \
        } SCB0; } while (0)
#define LDAH(b, i, h) do { \
        _Pragma("unroll") for (int mt = 2*(h); mt < 2*(h)+2; ++mt) { \
            const int r_ = wm * 128 + (i) * 64 + mt * 16 + mr; \
            _Pragma("unroll") for (int ks = 0; ks < 2; ++ks) \
                aF[mt][ks] = *(const v8bf*)&S[(b) * 16384 + r_ * 64 + \
                                    (((ks * 4 + q4) ^ (r_ & 7)) * 8)]; \
        } SCB0; } while (0)
#define MMAH(i, j, h) do { \
        _Pragma("unroll") for (int mt = 2*(h); mt < 2*(h)+2; ++mt) \
        _Pragma("unroll") for (int nt = 0; nt < 2; ++nt) \
        _Pragma("unroll") for (int ks = 0; ks < 2; ++ks) \
            acc[(i) * 4 + mt][(j) * 2 + nt] = \
                __builtin_amdgcn_mfma_f32_16x16x32_bf16(aF[mt][ks], bF[(j)][nt][ks], \
                    acc[(i) * 4 + mt][(j) * 2 + nt], 0, 0, 0); \
    } while (0)

    // prologue: tile0 complete + tile1 front strips
    STAGE_A(0, 0); STAGE_B(0, 0); STAGE_A(0, 1); STAGE_B(0, 1);
    STAGE_A(1, 0); STAGE_B(1, 0);
    VMW(4); BAR;

    for (int it = 0; it < KDIM / 128 - 1; ++it) {
        const int T = 2 * it;
        LDB(0,0); LDAH(0,0,0); LDAH(0,0,1); STAGE_A(T+1,1);
        BAR; LGKC(4); SP1; MMAH(0,0,0); LGKC(0); MMAH(0,0,1); SP0; BAR;
        LDB(0,1); STAGE_B(T+1,1);
        BAR; LGKC(0); SP1; MMAH(0,1,0); MMAH(0,1,1); SP0; BAR;
        LDAH(0,1,0); LDAH(0,1,1); STAGE_A(T+2,0);
        BAR; LGKC(4); SP1; MMAH(1,0,0); LGKC(0); MMAH(1,0,1); SP0; BAR;
        STAGE_B(T+2,0); VMW(4);
        BAR; SP1; MMAH(1,1,0); MMAH(1,1,1); SP0; BAR;
        LDB(1,0); LDAH(1,0,0); LDAH(1,0,1); STAGE_A(T+2,1);
        BAR; LGKC(4); SP1; MMAH(0,0,0); LGKC(0); MMAH(0,0,1); SP0; BAR;
        LDB(1,1); STAGE_B(T+2,1);
        BAR; LGKC(0); SP1; MMAH(0,1,0); MMAH(0,1,1); SP0; BAR;
        LDAH(1,1,0); LDAH(1,1,1); STAGE_A(T+3,0);
        BAR; LGKC(4); SP1; MMAH(1,0,0); LGKC(0); MMAH(1,0,1); SP0; BAR;
        STAGE_B(T+3,0); VMW(4);
        BAR; SP1; MMAH(1,1,0); MMAH(1,1,1); SP0; BAR;
    }
    // tail: tiles 30 (buf0), 31 (buf1)
    LDB(0,0); LDAH(0,0,0); LDAH(0,0,1); STAGE_A(31,1);
    BAR; LGKC(4); SP1; MMAH(0,0,0); LGKC(0); MMAH(0,0,1); SP0; BAR;
    LDB(0,1); STAGE_B(31,1);
    BAR; LGKC(0); SP1; MMAH(0,1,0); MMAH(0,1,1); SP0; BAR;
    LDAH(0,1,0); LDAH(0,1,1);
    BAR; LGKC(4); SP1; MMAH(1,0,0); LGKC(0); MMAH(1,0,1); SP0; BAR;
    VMW(0);
    BAR; SP1; MMAH(1,1,0); MMAH(1,1,1); SP0; BAR;
    LDB(1,0); LDAH(1,0,0); LDAH(1,0,1);
    BAR; LGKC(4); SP1; MMAH(0,0,0); LGKC(0); MMAH(0,0,1); SP0; BAR;
    LDB(1,1);
    BAR; LGKC(0); SP1; MMAH(0,1,0); MMAH(0,1,1); SP0; BAR;
    LDAH(1,1,0); LDAH(1,1,1);
    BAR; LGKC(4); SP1; MMAH(1,0,0); LGKC(0); MMAH(1,0,1); SP0; BAR;
    SP1; MMAH(1,1,0); MMAH(1,1,1); SP0;

    const int colb = bn * 256 + wn * 64 + mr;
    const int rowb = bm * 256 + wm * 128 + q4 * 4;
#pragma unroll
    for (int a = 0; a < 8; ++a) {
        const int ro = (a >> 2) * 64 + (a & 3) * 16;
#pragma unroll
        for (int r = 0; r < 4; ++r) {
            const long base = (long)(rowb + ro + r) * NDIM + colb;
#pragma unroll
            for (int c = 0; c < 4; ++c) {
                const float v = acc[a][c][r];
                const long off = base + (c >> 1) * 32 + (c & 1) * 16;
                if (mode == GM_STORE_F32)      Cf[off] = v;
                else if (mode == GM_ACC_F32)   Cf[off] += v;
                else                           Cb[off] = f2b(v);
            }
        }
    }
#undef STAGE_A
#undef STAGE_B
#undef LDB
#undef LDAH
#undef MMAH
}

// ---------------------------------------------------------------------------
// Fused K-projection: Kf = xh@W1^T + xh@W2^T + xl@W1^T  (f32 out, one pass).
// 256x256 tile, BK=32, 4 matrices staged (xh,xl,W1,W2): 64 KB/buffer, dbuf.
// 4 phases/K-tile, 24 MFMA/phase, counted vmcnt(4) (never drains mid-loop),
// counted lgkmcnt. Strip calendar (staged during tile T for tile T+1):
//   p0: A0   p1: B0   p2: B1   p3: A1    (deadlines: A0,B0@p0  B1@p1  A1@p2)
//   VMW(4) at ends of p0, p1, p3.
// LDS (u16 idx, per 32768-buffer): A: s*8192 + {xh:0, xl:4096}; B at +16384,
// s*8192 + {W1:0, W2:4096}. Row = 32 u16; chunk swizzle ck = q4^((mr^(mr>>2))&3).
// ---------------------------------------------------------------------------
__global__ __launch_bounds__(512, 2) void gemm_k3(const u16* __restrict__ Ah,
                                                  const u16* __restrict__ Al,
                                                  const u16* __restrict__ W1,
                                                  const u16* __restrict__ W2,
                                                  float* __restrict__ Cf)
{
    __shared__ __attribute__((aligned(16))) u16 S[65536];   // 128 KiB

    const int t    = threadIdx.x;
    const int swz  = (blockIdx.x & 7) * 32 + (blockIdx.x >> 3);
    const int bm   = swz >> 3, bn = swz & 7;
    const int lane = t & 63;
    const int wm   = (t >> 6) >> 2, wn = (t >> 6) & 3;
    const int mr   = lane & 15, q4 = lane >> 4;
    const int ck   = q4 ^ ((mr ^ (mr >> 2)) & 3);

    // staging geometry
    const int lr    = t >> 2;
    const int cks   = (t & 3) ^ ((lr ^ (lr >> 2)) & 3);
    const int growA = (lr & 63) + ((lr & 64) << 1);          // + s*64
    const int growB = (lr & 31) + ((lr >> 5) << 6);          // + s*32
    const u16* Ahp = Ah + (long)(bm * 256 + growA) * KDIM + cks * 8;
    const u16* Alp = Al + (long)(bm * 256 + growA) * KDIM + cks * 8;
    const u16* W1p = W1 + (long)(bn * 256 + growB) * KDIM + cks * 8;
    const u16* W2p = W2 + (long)(bn * 256 + growB) * KDIM + cks * 8;
    u16* dA = S +         lr * 32 + (t & 3) * 8;
    u16* dB = S + 16384 + lr * 32 + (t & 3) * 8;

#define K3SA(kt, s) do { \
        const long g_ = (long)(s) * 64 * KDIM + (kt) * 32; \
        u16* d_ = dA + (((kt) & 1) << 15) + (s) * 8192; \
        ASYNC16(Ahp + g_, d_); ASYNC16(Alp + g_, d_ + 4096); } while (0)
#define K3SB(kt, s) do { \
        const long g_ = (long)(s) * 32 * KDIM + (kt) * 32; \
        u16* d_ = dB + (((kt) & 1) << 15) + (s) * 8192; \
        ASYNC16(W1p + g_, d_); ASYNC16(W2p + g_, d_ + 4096); } while (0)

    v4f acc[8][4];
#pragma unroll
    for (int a = 0; a < 8; ++a)
#pragma unroll
        for (int c = 0; c < 4; ++c)
            acc[a][c] = (v4f){0.f, 0.f, 0.f, 0.f};

    v8bf aFh[4], aFl[4], b1[2][2], b2[2][2];
    const int aBase = wm * 2048 + mr * 32 + ck * 8;
    const int bBase = 16384 + wn * 1024 + mr * 32 + ck * 8;

#define K3RB(bb, j) do { \
        _Pragma("unroll") for (int nt = 0; nt < 2; ++nt) { \
            b1[j][nt] = *(const v8bf*)&S[(bb) + bBase + (j) * 8192 + nt * 512]; \
            b2[j][nt] = *(const v8bf*)&S[(bb) + bBase + (j) * 8192 + nt * 512 + 4096]; \
        } SCB0; } while (0)
#define K3RAH(bb, i) do { _Pragma("unroll") for (int mt = 0; mt < 4; ++mt) \
        aFh[mt] = *(const v8bf*)&S[(bb) + aBase + (i) * 8192 + mt * 512]; SCB0; } while (0)
#define K3RAL(bb, i) do { _Pragma("unroll") for (int mt = 0; mt < 4; ++mt) \
        aFl[mt] = *(const v8bf*)&S[(bb) + aBase + (i) * 8192 + mt * 512 + 4096]; SCB0; } while (0)
#define K3CL(af, bx, i, j) do { \
        _Pragma("unroll") for (int mt = 0; mt < 4; ++mt) \
        _Pragma("unroll") for (int nt = 0; nt < 2; ++nt) \
            acc[(i) * 4 + mt][(j) * 2 + nt] = __builtin_amdgcn_mfma_f32_16x16x32_bf16( \
                af[mt], bx[(j)][nt], acc[(i) * 4 + mt][(j) * 2 + nt], 0, 0, 0); } while (0)

    // prologue: tile0 strips in deadline order {A0,B0,B1,A1}
    K3SA(0, 0); K3SB(0, 0); K3SB(0, 1); K3SA(0, 1);
    VMW(4); BAR;

    for (int T = 0; T < KDIM / 32 - 1; ++T) {
        const int bb = (T & 1) << 15;
        // p0 : reads {B[0], Ah(0), Al(0)}; stage A0(T+1)
        K3RB(bb, 0); K3RAH(bb, 0); K3RAL(bb, 0); K3SA(T + 1, 0);
        BAR; LGKC(4); SP1; K3CL(aFh, b1, 0, 0); K3CL(aFh, b2, 0, 0);
        LGKC(0); K3CL(aFl, b1, 0, 0); SP0; VMW(4); BAR;
        // p1 : reads {B[1]}; stage B0(T+1)
        K3RB(bb, 1); K3SB(T + 1, 0);
        BAR; LGKC(0); SP1; K3CL(aFh, b1, 0, 1); K3CL(aFh, b2, 0, 1);
        K3CL(aFl, b1, 0, 1); SP0; VMW(4); BAR;
        // p2 : reads {Ah(1), Al(1)}; stage B1(T+1)
        K3RAH(bb, 1); K3RAL(bb, 1); K3SB(T + 1, 1);
        BAR; LGKC(4); SP1; K3CL(aFh, b1, 1, 0); K3CL(aFh, b2, 1, 0);
        LGKC(0); K3CL(aFl, b1, 1, 0); SP0; BAR;
        // p3 : no reads; stage A1(T+1)
        K3SA(T + 1, 1);
        BAR; SP1; K3CL(aFh, b1, 1, 1); K3CL(aFh, b2, 1, 1);
        K3CL(aFl, b1, 1, 1); SP0; VMW(4); BAR;
    }
    // tail tile 63 (bb = 32768); entering: outstanding = {B1(63), A1(63)}
    {
        const int bb = 32768;
        K3RB(bb, 0); K3RAH(bb, 0); K3RAL(bb, 0);
        BAR; LGKC(4); SP1; K3CL(aFh, b1, 0, 0); K3CL(aFh, b2, 0, 0);
        LGKC(0); K3CL(aFl, b1, 0, 0); SP0; VMW(2); BAR;
        K3RB(bb, 1);
        BAR; LGKC(0); SP1; K3CL(aFh, b1, 0, 1); K3CL(aFh, b2, 0, 1);
        K3CL(aFl, b1, 0, 1); SP0; VMW(0); BAR;
        K3RAH(bb, 1); K3RAL(bb, 1);
        BAR; LGKC(4); SP1; K3CL(aFh, b1, 1, 0); K3CL(aFh, b2, 1, 0);
        LGKC(0); K3CL(aFl, b1, 1, 0); SP0; BAR;
        SP1; K3CL(aFh, b1, 1, 1); K3CL(aFh, b2, 1, 1);
        K3CL(aFl, b1, 1, 1); SP0;
    }

    const int colb = bn * 256 + wn * 64 + mr;
    const int rowb = bm * 256 + wm * 128 + q4 * 4;
#pragma unroll
    for (int a = 0; a < 8; ++a) {
        const int ro = (a >> 2) * 64 + (a & 3) * 16;
#pragma unroll
        for (int r = 0; r < 4; ++r) {
            const long base = (long)(rowb + ro + r) * NDIM + colb;
#pragma unroll
            for (int c = 0; c < 4; ++c)
                Cf[base + (c >> 1) * 32 + (c & 1) * 16] = acc[a][c][r];
        }
    }
#undef K3SA
#undef K3SB
#undef K3RB
#undef K3RAH
#undef K3RAL
#undef K3CL
}

// ---------------------------------------------------------------------------
// Fused score net on fp32 K (selection-critical, stays fp32 VALU)
// ---------------------------------------------------------------------------
__global__ __launch_bounds__(256) void scorenet(const float* __restrict__ Kb,
                                                const float* __restrict__ sw1,
                                                const float* __restrict__ sb1,
                                                const float* __restrict__ sw2,
                                                const float* __restrict__ sb2,
                                                float* __restrict__ scores)
{
    __shared__ float As[16][128];
    __shared__ float Bs[16][128];
    __shared__ float red[128][17];
    const int t  = threadIdx.x;
    const int tx = t & 15, ty = t >> 4;
    const int bm = blockIdx.x;
    const int lr = t >> 1;
    const int lc = (t & 1) * 8;
    const float* Ap = Kb + (long)(bm * 128 + lr) * HD + lc;
    const float* Wp = sw1 + lr * HD + lc;

    float acc[8][8];
#pragma unroll
    for (int i = 0; i < 8; ++i)
#pragma unroll
        for (int j = 0; j < 8; ++j) acc[i][j] = 0.f;

    for (int k0 = 0; k0 < HD; k0 += 16) {
        float4 a0 = *(const float4*)(Ap + k0);
        float4 a1 = *(const float4*)(Ap + k0 + 4);
        float4 b0 = *(const float4*)(Wp + k0);
        float4 b1 = *(const float4*)(Wp + k0 + 4);
        __syncthreads();
        As[lc+0][lr] = a0.x; As[lc+1][lr] = a0.y; As[lc+2][lr] = a0.z; As[lc+3][lr] = a0.w;
        As[lc+4][lr] = a1.x; As[lc+5][lr] = a1.y; As[lc+6][lr] = a1.z; As[lc+7][lr] = a1.w;
        Bs[lc+0][lr] = b0.x; Bs[lc+1][lr] = b0.y; Bs[lc+2][lr] = b0.z; Bs[lc+3][lr] = b0.w;
        Bs[lc+4][lr] = b1.x; Bs[lc+5][lr] = b1.y; Bs[lc+6][lr] = b1.z; Bs[lc+7][lr] = b1.w;
        __syncthreads();
#pragma unroll
        for (int kk = 0; kk < 16; ++kk) {
            float a[8], b[8];
            *(float4*)&a[0] = *(const float4*)&As[kk][ty * 8];
            *(float4*)&a[4] = *(const float4*)&As[kk][ty * 8 + 4];
            *(float4*)&b[0] = *(const float4*)&Bs[kk][tx * 8];
            *(float4*)&b[4] = *(const float4*)&Bs[kk][tx * 8 + 4];
#pragma unroll
            for (int i = 0; i < 8; ++i)
#pragma unroll
                for (int j = 0; j < 8; ++j)
                    acc[i][j] = fmaf(a[i], b[j], acc[i][j]);
        }
    }

    float b1v[8], w2v[8];
#pragma unroll
    for (int j = 0; j < 8; ++j) {
        b1v[j] = sb1[tx * 8 + j];
        w2v[j] = sw2[tx * 8 + j];
    }
#pragma unroll
    for (int i = 0; i < 8; ++i) {
        float p = 0.f;
#pragma unroll
        for (int j = 0; j < 8; ++j)
            p += fmaxf(acc[i][j] + b1v[j], 0.f) * w2v[j];
        red[ty * 8 + i][tx] = p;
    }
    __syncthreads();
    if (t < 128) {
        float s = sb2[0];
#pragma unroll
        for (int c = 0; c < 16; ++c) s += red[t][c];
        long r = (long)bm * 128 + t;
        int b  = (int)(r >> 16);
        int si = (int)((r >> 4) & (SEQ - 1));
        int h  = (int)(r & (NH - 1));
        scores[((b * NH + h) << 12) + si] = s;
    }
}

// ---------------------------------------------------------------------------
// Exact top-128 per (b,h) via radix select; ties -> lowest indices.
// ---------------------------------------------------------------------------
__global__ __launch_bounds__(256) void topk_sel(const float* __restrict__ scores,
                                                int* __restrict__ sel)
{
    __shared__ unsigned keys[SEQ];
    __shared__ unsigned hist[256];
    __shared__ int scal2[2];
    __shared__ unsigned cntG;
    __shared__ unsigned short tpre[256];
    const int t  = threadIdx.x;
    const int bh = blockIdx.x;
    const float* sc = scores + (long)bh * SEQ;
    for (int i = t; i < SEQ; i += 256) {
        unsigned u = __float_as_uint(sc[i]);
        u = (u & 0x80000000u) ? ~u : (u | 0x80000000u);
        keys[i] = u;
    }
    unsigned prefix = 0;
    int rem = TOPK;
    const int i0 = t * 16;
    for (int shift = 24; shift >= 0; shift -= 8) {
        hist[t] = 0;
        __syncthreads();
        const unsigned pm = (shift == 24) ? 0u : (0xFFFFFFFFu << (shift + 8));
        for (int i = i0; i < i0 + 16; ++i) {
            unsigned k = keys[i];
            if (((k ^ prefix) & pm) == 0) atomicAdd(&hist[(k >> shift) & 255], 1u);
        }
        __syncthreads();
        if (t == 0) {
            int r = rem, chosen = 0;
            for (int b = 255; b >= 0; --b) {
                int c = (int)hist[b];
                if (c >= r) { chosen = b; break; }
                r -= c;
            }
            scal2[0] = chosen; scal2[1] = r;
        }
        __syncthreads();
        prefix |= ((unsigned)scal2[0]) << shift;
        rem = scal2[1];
        __syncthreads();
    }
    if (t == 0) cntG = 0;
    __syncthreads();
    const unsigned T = prefix;
    int myT = 0;
    for (int i = i0; i < i0 + 16; ++i) {
        unsigned k = keys[i];
        if (k > T) {
            unsigned p = atomicAdd(&cntG, 1u);
            sel[bh * TOPK + p] = i;
        } else if (k == T) myT++;
    }
    tpre[t] = (unsigned short)myT;
    __syncthreads();
    if (t == 0) {
        unsigned s = 0;
        for (int i = 0; i < 256; ++i) { unsigned c = tpre[i]; tpre[i] = (unsigned short)s; s += c; }
    }
    __syncthreads();
    const int base = TOPK - rem;
    int rank = tpre[t];
    for (int i = i0; i < i0 + 16; ++i) {
        if (keys[i] == T) {
            if (rank < rem) sel[bh * TOPK + base + rank] = i;
            rank++;
        }
    }
}

// ---------------------------------------------------------------------------
// Gather: K (fp32) -> ksb bf16 [bh][key][d] ; V (bf16) -> vsT bf16 [bh][d][key]
// ---------------------------------------------------------------------------
__global__ void gather_kv(const float* __restrict__ Kf, const u16* __restrict__ Vb,
                          const int* __restrict__ sel,
                          u16* __restrict__ ksb, u16* __restrict__ vsT)
{
    int bh = blockIdx.x >> 7;
    int j  = blockIdx.x & 127;
    int d  = threadIdx.x;
    int s  = sel[bh * TOPK + j];
    int b = bh >> 4, h = bh & (NH - 1);
    long src = ((long)(b * SEQ + s)) * NDIM + h * HD + d;
    ksb[((long)bh * TOPK + j) * HD + d] = f2b(Kf[src]);
    vsT[((long)bh * HD + d) * TOPK + j] = Vb[src];
}

// ---------------------------------------------------------------------------
// MFMA attention: block = 128 queries of one (b,h), 4 waves x 32 queries.
// ---------------------------------------------------------------------------
__device__ __forceinline__ int paddr(int row, int col) {   // u16 index into P
    int chunk = (col >> 3) ^ (row & 15);
    return row * 128 + chunk * 8 + (col & 7);
}

__global__ __launch_bounds__(256) void attn_mfma(const u16* __restrict__ Qb,
                                                 const u16* __restrict__ ksb,
                                                 const u16* __restrict__ vsT,
                                                 u16* __restrict__ outp)
{
    __shared__ __attribute__((aligned(16))) u16 P[128 * 128];  // 32 KB
    const int bh = blockIdx.x, qt = blockIdx.y;
    const int b = bh >> 4, h = bh & (NH - 1);
    const int t = threadIdx.x, lane = t & 63, w = t >> 6;
    const int mr = lane & 15, q4 = lane >> 4;
    const float scale = 0.08838834764831845f;   // 1/sqrt(128)

    const u16* q0p = Qb + ((long)(b * SEQ + qt * 128 + w * 32 + mr)) * NDIM
                        + h * HD + q4 * 8;
    v8bf aq[2][4];
#pragma unroll
    for (int ks = 0; ks < 4; ++ks) {
        aq[0][ks] = *(const v8bf*)(q0p + ks * 32);
        aq[1][ks] = *(const v8bf*)(q0p + 16 * NDIM + ks * 32);
    }

    const u16* kbase = ksb + (long)bh * TOPK * HD + mr * HD + q4 * 8;
    v4f acc[2][8];
#pragma unroll
    for (int i = 0; i < 2; ++i)
#pragma unroll
        for (int j = 0; j < 8; ++j) {
            acc[i][j][0] = 0.f; acc[i][j][1] = 0.f;
            acc[i][j][2] = 0.f; acc[i][j][3] = 0.f;
        }
#pragma unroll
    for (int ks = 0; ks < 4; ++ks) {
        v8bf bk[8];
#pragma unroll
        for (int nt = 0; nt < 8; ++nt)
            bk[nt] = *(const v8bf*)(kbase + (long)nt * 16 * HD + ks * 32);
#pragma unroll
        for (int mt = 0; mt < 2; ++mt)
#pragma unroll
            for (int nt = 0; nt < 8; ++nt)
                acc[mt][nt] = __builtin_amdgcn_mfma_f32_16x16x32_bf16(
                                  aq[mt][ks], bk[nt], acc[mt][nt], 0, 0, 0);
    }

#pragma unroll
    for (int mt = 0; mt < 2; ++mt)
#pragma unroll
        for (int r = 0; r < 4; ++r) {
            float mx = acc[mt][0][r];
#pragma unroll
            for (int nt = 1; nt < 8; ++nt) mx = fmaxf(mx, acc[mt][nt][r]);
#pragma unroll
            for (int m = 1; m < 16; m <<= 1) mx = fmaxf(mx, __shfl_xor(mx, m));
            float sum = 0.f;
#pragma unroll
            for (int nt = 0; nt < 8; ++nt) {
                float e = __expf((acc[mt][nt][r] - mx) * scale);
                acc[mt][nt][r] = e; sum += e;
            }
#pragma unroll
            for (int m = 1; m < 16; m <<= 1) sum += __shfl_xor(sum, m);
            float inv = 1.f / sum;
#pragma unroll
            for (int nt = 0; nt < 8; ++nt) acc[mt][nt][r] *= inv;
        }

#pragma unroll
    for (int mt = 0; mt < 2; ++mt)
#pragma unroll
        for (int nt = 0; nt < 8; ++nt)
#pragma unroll
            for (int r = 0; r < 4; ++r)
                P[paddr(w * 32 + mt * 16 + q4 * 4 + r, nt * 16 + mr)] =
                    f2b(acc[mt][nt][r]);
    __syncthreads();

    const u16* vbase = vsT + (long)bh * HD * TOPK + mr * TOPK + q4 * 8;
    v4f acc2[2][8];
#pragma unroll
    for (int i = 0; i < 2; ++i)
#pragma unroll
        for (int j = 0; j < 8; ++j) {
            acc2[i][j][0] = 0.f; acc2[i][j][1] = 0.f;
            acc2[i][j][2] = 0.f; acc2[i][j][3] = 0.f;
        }
#pragma unroll
    for (int ks = 0; ks < 4; ++ks) {
        v8bf ap[2];
        ap[0] = *(const v8bf*)&P[paddr(w * 32 + mr,      ks * 32 + q4 * 8)];
        ap[1] = *(const v8bf*)&P[paddr(w * 32 + 16 + mr, ks * 32 + q4 * 8)];
        v8bf bv[8];
#pragma unroll
        for (int nt = 0; nt < 8; ++nt)
            bv[nt] = *(const v8bf*)(vbase + (long)nt * 16 * TOPK + ks * 32);
#pragma unroll
        for (int mt = 0; mt < 2; ++mt)
#pragma unroll
            for (int nt = 0; nt < 8; ++nt)
                acc2[mt][nt] = __builtin_amdgcn_mfma_f32_16x16x32_bf16(
                                   ap[mt], bv[nt], acc2[mt][nt], 0, 0, 0);
    }
    __syncthreads();

#pragma unroll
    for (int mt = 0; mt < 2; ++mt)
#pragma unroll
        for (int nt = 0; nt < 8; ++nt)
#pragma unroll
            for (int r = 0; r < 4; ++r)
                P[paddr(w * 32 + mt * 16 + q4 * 4 + r, nt * 16 + mr)] =
                    f2b(acc2[mt][nt][r]);
    __syncthreads();

    u16* obase = outp + ((long)(b * SEQ + qt * 128)) * NDIM + h * HD;
    for (int f = t; f < 2048; f += 256) {
        int row = f >> 4, cc = f & 15;
        uint4 val = *(const uint4*)&P[row * 128 + (cc ^ (row & 15)) * 8];
        *(uint4*)(obase + (long)row * NDIM + cc * 8) = val;
    }
}

// ---------------------------------------------------------------------------
extern "C" void kernel_launch(void* const* d_in, const int* in_sizes, int n_in,
                              void* d_out, int out_size, void* d_ws, size_t ws_size,
                              hipStream_t stream)
{
    const float* x   = (const float*)d_in[0];
    const float* wq  = (const float*)d_in[1];
    const float* wk  = (const float*)d_in[2];
    const float* wv  = (const float*)d_in[3];
    const float* wo  = (const float*)d_in[4];
    const float* sw1 = (const float*)d_in[5];
    const float* sb1 = (const float*)d_in[6];
    const float* sw2 = (const float*)d_in[7];
    const float* sb2 = (const float*)d_in[8];
    float* out = (float*)d_out;

    // workspace layout (bytes), ~179.5 MiB total
    char* base = (char*)d_ws;
    u16*   xh      = (u16*)  base;                     // 33,554,432
    u16*   xl      = (u16*) (base + 33554432L);        // 33,554,432 (later: Qb)
    float* Kf      = (float*)(base + 67108864L);       // 67,108,864
    u16*   Vb      = (u16*) (base + 134217728L);       // 33,554,432 (later: AOb)
    u16*   W1      = (u16*) (base + 167772160L);       // 8,388,608
    u16*   W2      = (u16*) (base + 176160768L);       // 8,388,608
    float* scoresB = (float*)(base + 184549376L);      // 524,288
    int*   sel     = (int*) (base + 185073664L);       // 16,384
    u16*   ksb     = (u16*) (base + 185090048L);       // 1,048,576
    u16*   vsT     = (u16*) (base + 186138624L);       // 1,048,576
    u16*   Qb      = xl;                               // alias: xl dead after K pass
    u16*   AOb     = Vb;                               // alias: Vb dead after gather

    const long NX = (long)MDIM * NDIM;
    dim3 blk(256);
    const int g256 = (MDIM / 256) * (NDIM / 256);      // 256 blocks, 1/CU

    // precision splits / casts
    split_f32<<<16384, blk, 0, stream>>>(x,  xh, xl, NX);
    split_f32<<<4096,  blk, 0, stream>>>(wk, W1, W2, (long)NDIM * KDIM);
    // K = xh@wkh^T + xh@wkl^T + xl@wkh^T fused in one pass (fp32 acc in regs)
    gemm_k3<<<g256, 512, 0, stream>>>(xh, xl, W1, W2, Kf);
    // Q, V in plain bf16
    cvt_bf16<<<4096, blk, 0, stream>>>(wq, W1, (long)NDIM * KDIM);
    cvt_bf16<<<4096, blk, 0, stream>>>(wv, W2, (long)NDIM * KDIM);
    gemm256<<<g256, 512, 0, stream>>>(xh, W1, nullptr, Qb, GM_STORE_B16);
    gemm256<<<g256, 512, 0, stream>>>(xh, W2, nullptr, Vb, GM_STORE_B16);
    // selection path (fp32 K)
    scorenet<<<(MDIM * NH) / 128, blk, 0, stream>>>(Kf, sw1, sb1, sw2, sb2, scoresB);
    topk_sel<<<NB * NH, blk, 0, stream>>>(scoresB, sel);
    gather_kv<<<NB * NH * TOPK, 128, 0, stream>>>(Kf, Vb, sel, ksb, vsT);
    // MFMA attention -> AOb
    attn_mfma<<<dim3(NB * NH, SEQ / 128), blk, 0, stream>>>(Qb, ksb, vsT, AOb);
    // output projection
    cvt_bf16<<<4096, blk, 0, stream>>>(wo, W1, (long)NDIM * KDIM);
    gemm256<<<g256, 512, 0, stream>>>(AOb, W1, out, nullptr, GM_STORE_F32);
}